// Round 10
// baseline (55.786 us; speedup 1.0000x reference)
//
#include <hip/hip_runtime.h>

// Adaptive mean thresholding: out = (x > mean11x11(x) - 2) ? 0 : 255, replicate border.
// BIT-EXACT contract (verified absmax=0.0 rounds 3-9): vertical 11-tap f32 FMA
// chain (ascending row order, weight (float)(1.0/11.0)), rounded to f32; then
// horizontal 11-tap f32 FMA chain (ascending col order); thresh = m - 2.0f;
// decision x > thresh. Replicate-border mv values are bitwise duplicates of the
// edge col's chain (synthesized by duplication, never recomputed).
//
// R10 = R8 (best profiled efficiency: VGPR 28, occ 75%, VALUBusy 52%, 0 bank
// conflicts) + memory-system tuning only:
//  - depth-2 register prefetch (p/q rotation, static indices): 4 loads in
//    flight per thread; vmcnt never drains at the consume point.
//  - bijective XCD-chunked swizzle (2048 blocks -> 256 consecutive strips =
//    16 whole images per XCD): adjacent strips co-run on one XCD, halo rows
//    (31% re-read) become L2 hits.
//  - NO min-waves clamp (R7: forced VGPR=64 spilled the ring, FETCH x4.4).
//    NO NT stores (R5: WRITE 131->248 MB).

constexpr int W   = 512;
constexpr int H   = 512;
constexpr int PAD = 5;            // (11-1)/2
constexpr int KS  = 11;
constexpr int TPB = 256;          // cols t and t+256 per thread
constexpr int RPB = 32;           // output rows per block
constexpr int WP  = W + 2 * PAD;  // 522 padded columns
constexpr int SPI = H / RPB;      // 16 strips per image
constexpr int NXCD = 8;

__global__ __launch_bounds__(TPB)
void AdaptiveThresholding_57904749085171_kernel(const float* __restrict__ x,
                                                float* __restrict__ out)
{
    __shared__ float mv[2][WP];    // double-buffered vertical-pass row (4.2 KB)

    const int t  = (int)threadIdx.x;
    const int cA = t;
    const int cB = t + 256;

    // XCD-chunked bijective swizzle: 2048 blocks, 256 per XCD, consecutive
    // strips (same/adjacent images) share an XCD's L2.
    const int bid = (int)blockIdx.x;
    const int cpx = (int)gridDim.x / NXCD;          // 256
    const int strip = (bid % NXCD) * cpx + bid / NXCD;

    const int img = strip / SPI;
    const int y0  = (strip % SPI) * RPB;
    const size_t ioff = (size_t)img * (size_t)(W * H);
    const float* __restrict__ xi = x + ioff;
    float* __restrict__ oi = out + ioff;
    const float wv = (float)(1.0 / 11.0);

    // Register ring: rows y-5 .. y+5 for this thread's two columns (static idx).
    float r0[KS], r1[KS];

    // ---- prologue: virtual rows y0-5 .. y0+4 -> r[0..9] ----
    #pragma unroll
    for (int k = 0; k < KS - 1; ++k) {
        int j = y0 - PAD + k;
        int src = j < 0 ? 0 : (j >= H ? H - 1 : j);
        const float* rp = xi + (size_t)src * W;
        r0[k] = rp[cA];
        r1[k] = rp[cB];
    }
    // depth-2 prefetch: p = row y0+5, q = row y0+6 (clamped)
    float p0, p1, q0, q1;
    {
        int j = y0 + PAD;      int src = j >= H ? H - 1 : j;
        const float* rp = xi + (size_t)src * W;
        p0 = rp[cA]; p1 = rp[cB];
    }
    {
        int j = y0 + PAD + 1;  int src = j >= H ? H - 1 : j;
        const float* rp = xi + (size_t)src * W;
        q0 = rp[cA]; q1 = rp[cB];
    }

    for (int y = y0; y < y0 + RPB; ++y) {
        // complete the ring: r[10] = row y+5 (prefetched 2 iterations ago)
        r0[KS - 1] = p0;
        r1[KS - 1] = p1;
        // rotate pipeline: p <- q
        p0 = q0; p1 = q1;
        // issue load for row y+7 (clamped; harmless L2 hit when past strip end)
        {
            int j = y + PAD + 2;  int src = j >= H ? H - 1 : j;
            const float* rp = xi + (size_t)src * W;
            q0 = rp[cA]; q1 = rp[cB];
        }

        // ---- vertical f32 FMA chains (ascending row order) ----
        float a0 = 0.0f, a1 = 0.0f;
        #pragma unroll
        for (int d = 0; d < KS; ++d) {
            a0 = fmaf(r0[d], wv, a0);
            a1 = fmaf(r1[d], wv, a1);
        }

        const int pp = (y - y0) & 1;
        mv[pp][PAD + cA] = a0;                 // lane-consecutive: conflict-free
        mv[pp][PAD + cB] = a1;
        if (t == 0) {
            #pragma unroll
            for (int i = 0; i < PAD; ++i) mv[pp][i] = a0;           // == col-0 mv
        } else if (t == TPB - 1) {
            #pragma unroll
            for (int i = 0; i < PAD; ++i) mv[pp][W + PAD + i] = a1; // == col-511 mv
        }

        // center row value (row y) before shifting
        const float xv0 = r0[PAD];
        const float xv1 = r1[PAD];

        // ---- shift ring (static indices) ----
        #pragma unroll
        for (int d = 0; d < KS - 1; ++d) {
            r0[d] = r0[d + 1];
            r1[d] = r1[d + 1];
        }

        __syncthreads();   // mv[pp] visible to all waves

        // ---- horizontal f32 FMA chains (ascending col order) + decision ----
        float m0 = 0.0f, m1 = 0.0f;
        #pragma unroll
        for (int e = 0; e < KS; ++e) m0 = fmaf(mv[pp][cA + e], wv, m0);
        #pragma unroll
        for (int e = 0; e < KS; ++e) m1 = fmaf(mv[pp][cB + e], wv, m1);

        float* op = oi + (size_t)y * W;
        op[cA] = (xv0 > m0 - 2.0f) ? 0.0f : 255.0f;
        op[cB] = (xv1 > m1 - 2.0f) ? 0.0f : 255.0f;
        // no second barrier: next iter writes mv[pp^1]; mv[pp] is overwritten
        // only at iter y+2, after all threads pass barrier(y+1).
    }
}

extern "C" void kernel_launch(void* const* d_in, const int* in_sizes, int n_in,
                              void* d_out, int out_size, void* d_ws, size_t ws_size,
                              hipStream_t stream)
{
    const float* x = (const float*)d_in[0];
    float* out = (float*)d_out;
    const int n_imgs = in_sizes[0] / (W * H);   // 128

    dim3 grid((unsigned)(n_imgs * SPI));   // 2048 blocks (1-D for the swizzle)
    dim3 block(TPB);
    AdaptiveThresholding_57904749085171_kernel<<<grid, block, 0, stream>>>(x, out);
}